// Round 6
// baseline (857.746 us; speedup 1.0000x reference)
//
#include <hip/hip_runtime.h>
#include <math.h>

#define S 256
#define D 512
#define P 16
#define NIJ (D*D)
#define GCAP 8192

__device__ __forceinline__ float gelu_f(float x){ return 0.5f*x*(1.f+erff(x*0.70710678118654752f)); }
__device__ __forceinline__ float silu_f(float x){ return x/(1.f+expf(-x)); }
__device__ __forceinline__ float sigm_f(float x){ return 1.f/(1.f+expf(-x)); }

// K1: LayerNorm + RoPE per row
__global__ void __launch_bounds__(256) k_ln_rope(const float* __restrict__ x,
    const float* __restrict__ g, const float* __restrict__ b,
    float* __restrict__ xn, float* __restrict__ xr){
  int s2 = blockIdx.x, tid = threadIdx.x;
  __shared__ float red[256];
  __shared__ float xnl[512];
  const float* xrow = x + s2*D;
  float v0 = xrow[tid], v1 = xrow[tid+256];
  red[tid] = v0+v1; __syncthreads();
  for (int st=128; st>0; st>>=1){ if (tid<st) red[tid]+=red[tid+st]; __syncthreads(); }
  float mean = red[0]*(1.f/512.f); __syncthreads();
  float d0=v0-mean, d1=v1-mean;
  red[tid]=d0*d0+d1*d1; __syncthreads();
  for (int st=128; st>0; st>>=1){ if (tid<st) red[tid]+=red[tid+st]; __syncthreads(); }
  float var = red[0]*(1.f/512.f);
  float rstd = rsqrtf(var+1e-5f);
  float a0 = d0*rstd*g[tid]+b[tid];
  float a1 = d1*rstd*g[tid+256]+b[tid+256];
  xn[s2*D+tid]=a0; xn[s2*D+tid+256]=a1;
  xnl[tid]=a0; xnl[tid+256]=a1;
  __syncthreads();
  int j = tid;
  float e = (float)(2*j)*(1.f/512.f);
  float inv = 1.f/powf(10000.f, e);
  float ang = (float)s2 * inv;
  float c = cosf(ang), sn = sinf(ang);
  float p0 = xnl[2*j], p1 = xnl[2*j+1];
  xr[s2*D+2*j]   = p0*c - p1*sn;
  xr[s2*D+2*j+1] = p1*c + p0*sn;
}

// K2: column means
__global__ void __launch_bounds__(256) k_colmean(const float* __restrict__ xr,
    const float* __restrict__ bank, float* __restrict__ meanxr, float* __restrict__ memmean){
  int tid=threadIdx.x;
  if (blockIdx.x<2){
    int d2 = blockIdx.x*256+tid; float acc=0.f;
    for (int s2=0;s2<S;++s2) acc += xr[s2*D+d2];
    meanxr[d2]=acc*(1.f/256.f);
  } else {
    int d2=(blockIdx.x-2)*256+tid; float acc=0.f;
    for (int r=0;r<512;++r) acc += bank[r*D+d2];
    memmean[d2]=acc*(1.f/512.f);
  }
}

// K3: window MLP -> kk; fold ctx/mem halves into effective biases
__global__ void __launch_bounds__(256) k_head(const float* __restrict__ meanxr, const float* __restrict__ memmean,
    const float* __restrict__ ww1, const float* __restrict__ wb1,
    const float* __restrict__ ww2, const float* __restrict__ wb2,
    const float* __restrict__ sw1, const float* __restrict__ sb1,
    const float* __restrict__ iw1, const float* __restrict__ ib1,
    const float* __restrict__ mw1, const float* __restrict__ mb1,
    float* __restrict__ ctxsel, float* __restrict__ ctxint,
    float* __restrict__ mempart, int* __restrict__ kkout){
  int tid=threadIdx.x;
  __shared__ float mx[512], mm[512], gw[64];
  mx[tid]=meanxr[tid]; mx[tid+256]=meanxr[tid+256];
  mm[tid]=memmean[tid]; mm[tid+256]=memmean[tid+256];
  __syncthreads();
  if (tid<64){ float a=wb1[tid]; for (int d2=0;d2<512;++d2) a=fmaf(mx[d2], ww1[d2*64+tid], a); gw[tid]=gelu_f(a); }
  __syncthreads();
  if (tid==0){
    float a=wb2[0]; for (int h=0;h<64;++h) a=fmaf(gw[h], ww2[h], a);
    float win = sigm_f(a)*3840.f+256.f;
    float asp = 0.1f*(win*(1.f/4096.f));
    float t = 262144.f*asp;
    int kk=(int)t; if (kk<1) kk=1;
    *kkout=kk;
  }
  if (tid<32){ float a=sb1[tid]; for (int d2=0;d2<512;++d2) a=fmaf(mx[d2], sw1[(512+d2)*32+tid], a); ctxsel[tid]=a; }
  if (tid>=64 && tid<128){ int o=tid-64; float a=ib1[o]; for (int d2=0;d2<512;++d2) a=fmaf(mx[d2], iw1[(512+d2)*64+o], a); ctxint[o]=a; }
  for (int o=tid;o<512;o+=256){ float a=mb1[o]; for (int d2=0;d2<512;++d2) a=fmaf(mm[d2], mw1[(512+d2)*512+o], a); mempart[o]=a; }
}

// K4: per-position selection MLP (softmax pw) + intensity
__global__ void __launch_bounds__(256) k_selint(const float* __restrict__ xr,
    const float* __restrict__ ctxsel, const float* __restrict__ ctxint,
    const float* __restrict__ sw1, const float* __restrict__ sw2, const float* __restrict__ sb2,
    const float* __restrict__ iw1, const float* __restrict__ iw2, const float* __restrict__ ib2,
    float* __restrict__ pw, float* __restrict__ inten){
  int s2=blockIdx.x, tid=threadIdx.x;
  __shared__ float xl[512]; __shared__ float h1[32], h2[64], lg[16];
  xl[tid]=xr[s2*D+tid]; xl[tid+256]=xr[s2*D+tid+256];
  __syncthreads();
  if (tid<32){ float a=ctxsel[tid]; for (int d2=0;d2<512;++d2) a=fmaf(xl[d2], sw1[d2*32+tid], a); h1[tid]=gelu_f(a); }
  else if (tid<96){ int o=tid-32; float a=ctxint[o]; for (int d2=0;d2<512;++d2) a=fmaf(xl[d2], iw1[d2*64+o], a); h2[o]=gelu_f(a); }
  __syncthreads();
  if (tid<16){ float a=sb2[tid]; for (int h=0;h<32;++h) a=fmaf(h1[h], sw2[h*16+tid], a); lg[tid]=a; }
  __syncthreads();
  if (tid==0){
    float m=lg[0]; for (int p2=1;p2<16;++p2) m=fmaxf(m,lg[p2]);
    float sm=0.f; float e[16];
    for (int p2=0;p2<16;++p2){ e[p2]=expf(lg[p2]-m); sm+=e[p2]; }
    float r=1.f/sm;
    for (int p2=0;p2<16;++p2) pw[s2*16+p2]=e[p2]*r;
  }
  if (tid==64){ float a=ib2[0]; for (int h=0;h<64;++h) a=fmaf(h2[h], iw2[h], a); inten[s2]=sigm_f(a); }
}

// K5a: shared-sweep histogram. grid (64 pos-groups, 4 chunks); 4 positions/block.
// 13-bit bins (abs bits >> 18). LDS 4x8192 u32 = 128KB.
__global__ void __launch_bounds__(1024) k_fhist(const float* __restrict__ pat,
    const float* __restrict__ pw, unsigned* __restrict__ ghist){
  __shared__ unsigned hist[4*8192];
  __shared__ float pws4[64];
  int g=blockIdx.x, c=blockIdx.y, tid=threadIdx.x;
  if (tid<64) pws4[tid]=pw[g*64+tid];
  for (int i=tid;i<32768;i+=1024) hist[i]=0u;
  __syncthreads();
  const float4* patv=(const float4*)pat;
  int base=c*16384;
  for (int it=0;it<16;++it){
    int f4=base+(it<<10)+tid;
    float4 pv[16];
    #pragma unroll
    for (int p=0;p<16;++p) pv[p]=patv[(p<<16)+f4];
    #pragma unroll
    for (int pp=0;pp<4;++pp){
      float4 a=make_float4(0.f,0.f,0.f,0.f);
      #pragma unroll
      for (int p=0;p<16;++p){
        float w=pws4[(pp<<4)+p];
        a.x=fmaf(w,pv[p].x,a.x); a.y=fmaf(w,pv[p].y,a.y);
        a.z=fmaf(w,pv[p].z,a.z); a.w=fmaf(w,pv[p].w,a.w);
      }
      unsigned* h=&hist[pp<<13];
      atomicAdd(&h[(__float_as_uint(a.x)&0x7fffffffu)>>18],1u);
      atomicAdd(&h[(__float_as_uint(a.y)&0x7fffffffu)>>18],1u);
      atomicAdd(&h[(__float_as_uint(a.z)&0x7fffffffu)>>18],1u);
      atomicAdd(&h[(__float_as_uint(a.w)&0x7fffffffu)>>18],1u);
    }
  }
  __syncthreads();
  for (int i=tid;i<32768;i+=1024){
    unsigned v=hist[i];
    if (v) atomicAdd(&ghist[(((g<<2)+(i>>13))<<13)+(i&8191)], v);
  }
}

// K5b: per-position threshold bin from 8192-bin global histogram.
__global__ void __launch_bounds__(256) k_fth(const unsigned* __restrict__ ghist,
    const int* __restrict__ kkin, unsigned* __restrict__ meta){
  int pos=blockIdx.x, tid=threadIdx.x;
  __shared__ unsigned part[256]; __shared__ unsigned sup[16];
  const unsigned* h=ghist+(pos<<13);
  unsigned s=0;
  for (int k=0;k<32;++k) s+=h[tid*32+k];
  part[tid]=s; __syncthreads();
  if (tid<16){ unsigned t=0; for (int k=0;k<16;++k) t+=part[tid*16+k]; sup[tid]=t; }
  __syncthreads();
  if (tid==0){
    unsigned kk=(unsigned)(*kkin);
    unsigned cum=0; int u=0;
    for (int j=15;j>=0;--j){ if (cum+sup[j]>=kk){ u=j; break; } cum+=sup[j]; }
    int t=u*16;
    for (int j=u*16+15;j>=u*16;--j){ if (cum+part[j]>=kk){ t=j; break; } cum+=part[j]; }
    int b=t*32;
    for (int j=t*32+31;j>=t*32;--j){ if (cum+h[j]>=kk){ b=j; break; } cum+=h[j]; }
    meta[pos*4+0]=(unsigned)b; meta[pos*4+1]=kk-cum; meta[pos*4+2]=h[b];
  }
}

// K5c: shared-sweep masked matvec + candidate stash. grid (64,4).
__global__ void __launch_bounds__(1024) k_fmv(const float* __restrict__ pat,
    const float* __restrict__ pw, const float* __restrict__ xn,
    const unsigned* __restrict__ meta, float* __restrict__ goutr,
    unsigned* __restrict__ gbits, float* __restrict__ gcon,
    unsigned short* __restrict__ grow, unsigned* __restrict__ gcount){
  __shared__ float pws4[64];
  __shared__ float xnl[2048];
  __shared__ float outr[2048];
  int g=blockIdx.x, c=blockIdx.y, tid=threadIdx.x;
  if (tid<64) pws4[tid]=pw[g*64+tid];
  for (int i=tid;i<2048;i+=1024){ xnl[i]=xn[(g<<11)+i]; outr[i]=0.f; }
  __syncthreads();
  unsigned bst[4]; bool incl[4];
  #pragma unroll
  for (int pp=0;pp<4;++pp){
    bst[pp]=meta[((g<<2)+pp)*4];
    incl[pp]=meta[((g<<2)+pp)*4+2]>GCAP;
  }
  const float4* patv=(const float4*)pat;
  int base=c*16384;
  for (int it=0;it<16;++it){
    int f4=base+(it<<10)+tid;
    float4 pv[16];
    #pragma unroll
    for (int p=0;p<16;++p) pv[p]=patv[(p<<16)+f4];
    int e0=f4<<2;
    int row=e0>>9, col0=e0&511;
    #pragma unroll
    for (int pp=0;pp<4;++pp){
      float4 a=make_float4(0.f,0.f,0.f,0.f);
      #pragma unroll
      for (int p=0;p<16;++p){
        float w=pws4[(pp<<4)+p];
        a.x=fmaf(w,pv[p].x,a.x); a.y=fmaf(w,pv[p].y,a.y);
        a.z=fmaf(w,pv[p].z,a.z); a.w=fmaf(w,pv[p].w,a.w);
      }
      float vv[4]={a.x,a.y,a.z,a.w};
      float lacc=0.f;
      #pragma unroll
      for (int q=0;q<4;++q){
        unsigned bits=__float_as_uint(vv[q])&0x7fffffffu;
        unsigned pfx=bits>>18;
        if (pfx>bst[pp] || (incl[pp]&&pfx==bst[pp])) lacc=fmaf(vv[q], xnl[(pp<<9)+col0+q], lacc);
        else if (pfx==bst[pp]){
          unsigned idx=atomicAdd(&gcount[(g<<2)+pp],1u);
          if (idx<GCAP){
            int o=(((g<<2)+pp)<<13)+idx;
            gbits[o]=bits; gcon[o]=vv[q]*xnl[(pp<<9)+col0+q]; grow[o]=(unsigned short)row;
          }
        }
      }
      if (lacc!=0.f) atomicAdd(&outr[(pp<<9)+row], lacc);
    }
  }
  __syncthreads();
  for (int i=tid;i<2048;i+=1024){
    float v=outr[i];
    if (v!=0.f) atomicAdd(&goutr[(g<<11)+i], v);
  }
}

// K5d: per-position exact refinement over candidates + apply + residual + LN2.
__global__ void __launch_bounds__(256) k_fref(const float* __restrict__ x,
    const float* __restrict__ goutr, const unsigned* __restrict__ meta,
    const unsigned* __restrict__ gcount, const unsigned* __restrict__ gbits,
    const float* __restrict__ gcon, const unsigned short* __restrict__ grow,
    const float* __restrict__ inten, const float* __restrict__ n2g, const float* __restrict__ n2b,
    float* __restrict__ co){
  int pos=blockIdx.x, tid=threadIdx.x;
  __shared__ float outr[512]; __shared__ unsigned rhist[2048]; __shared__ unsigned rpart[128];
  __shared__ unsigned thsh[4]; __shared__ float red[256];
  outr[tid]=goutr[pos*512+tid]; outr[tid+256]=goutr[pos*512+tid+256];
  unsigned bstar=meta[pos*4], rnk=meta[pos*4+1], cnt=meta[pos*4+2];
  bool incl=cnt>GCAP;
  if (!incl){
    unsigned n=gcount[pos]; if (n>GCAP) n=GCAP;
    const unsigned* cb=gbits+(pos<<13);
    const float* cc=gcon+(pos<<13);
    const unsigned short* cr=grow+(pos<<13);
    for (int i=tid;i<2048;i+=256) rhist[i]=0u;
    __syncthreads();
    for (unsigned i=tid;i<n;i+=256) atomicAdd(&rhist[(cb[i]>>7)&0x7ffu],1u);
    __syncthreads();
    if (tid<128){ unsigned t=0;
      #pragma unroll
      for (int k=0;k<16;++k) t+=rhist[tid*16+k];
      rpart[tid]=t; }
    __syncthreads();
    if (tid==0){
      unsigned cum=0; int rp=0;
      for (int j=127;j>=0;--j){ if (cum+rpart[j]>=rnk){ rp=j; break; } cum+=rpart[j]; }
      int sub=rp*16;
      for (int j=rp*16+15;j>=rp*16;--j){ if (cum+rhist[j]>=rnk){ sub=j; break; } cum+=rhist[j]; }
      thsh[0]=(unsigned)sub; thsh[1]=rnk-cum;
    }
    __syncthreads();
    unsigned sub=thsh[0], r2=thsh[1];
    if (tid<128) rhist[tid]=0u;
    __syncthreads();
    for (unsigned i=tid;i<n;i+=256) if (((cb[i]>>7)&0x7ffu)==sub) atomicAdd(&rhist[cb[i]&127u],1u);
    __syncthreads();
    if (tid==0){
      unsigned cum=0; unsigned lo=0;
      for (int j=127;j>=0;--j){ if (cum+rhist[j]>=r2){ lo=(unsigned)j; break; } cum+=rhist[j]; }
      thsh[2]=(bstar<<18)|(sub<<7)|lo;
    }
    __syncthreads();
    unsigned thb=thsh[2];
    for (unsigned i=tid;i<n;i+=256) if (cb[i]>=thb) atomicAdd(&outr[cr[i]], cc[i]);
  }
  __syncthreads();
  float it=inten[pos];
  float t0=x[pos*D+tid]+outr[tid]*it;
  float t1=x[pos*D+tid+256]+outr[tid+256]*it;
  red[tid]=t0+t1; __syncthreads();
  for (int st=128;st>0;st>>=1){ if (tid<st) red[tid]+=red[tid+st]; __syncthreads(); }
  float mean=red[0]*(1.f/512.f); __syncthreads();
  float d0=t0-mean, d1=t1-mean;
  red[tid]=d0*d0+d1*d1; __syncthreads();
  for (int st=128;st>0;st>>=1){ if (tid<st) red[tid]+=red[tid+st]; __syncthreads(); }
  float var=red[0]*(1.f/512.f);
  float rstd=rsqrtf(var+1e-5f);
  co[pos*D+tid]=d0*rstd*n2g[tid]+n2b[tid];
  co[pos*D+tid+256]=d1*rstd*n2g[tid+256]+n2b[tid+256];
}

// ---------------- GEMM: 32x64 tile, LDS-staged, prefetch, 4x2 reg tile ----------------
template<int ACT, int RES>
__global__ void __launch_bounds__(256) k_gemm2(const float* __restrict__ A, const float* __restrict__ W,
    const float* __restrict__ bias, const float* __restrict__ res,
    float* __restrict__ C, int K, int N){
  __shared__ float Ast[32][36];
  __shared__ float Ws[32][68];
  int tid=threadIdx.x;
  int cb=blockIdx.x<<6;
  int s0=blockIdx.y<<5;
  int rid=tid>>5;
  int cid=tid&31;
  int arow=tid>>3, akq=tid&7;
  int wrow=tid>>4, wc4=tid&15;
  float acc[4][2]={{0.f,0.f},{0.f,0.f},{0.f,0.f},{0.f,0.f}};
  const float* Aptr = A + (size_t)(s0+arow)*K + (akq<<2);
  const float* Wptr0 = W + (size_t)wrow*N + cb + (wc4<<2);
  const float* Wptr1 = W + (size_t)(wrow+16)*N + cb + (wc4<<2);
  float4 av=*(const float4*)Aptr;
  float4 w0=*(const float4*)Wptr0;
  float4 w1=*(const float4*)Wptr1;
  for (int k0=0;k0<K;k0+=32){
    Ast[(akq<<2)+0][arow]=av.x; Ast[(akq<<2)+1][arow]=av.y;
    Ast[(akq<<2)+2][arow]=av.z; Ast[(akq<<2)+3][arow]=av.w;
    *(float4*)&Ws[wrow][wc4<<2]=w0;
    *(float4*)&Ws[wrow+16][wc4<<2]=w1;
    __syncthreads();
    if (k0+32<K){
      av=*(const float4*)(Aptr + k0+32);
      w0=*(const float4*)(Wptr0 + (size_t)(k0+32)*N);
      w1=*(const float4*)(Wptr1 + (size_t)(k0+32)*N);
    }
    #pragma unroll
    for (int kk=0;kk<32;++kk){
      float4 a4=*(const float4*)&Ast[kk][rid<<2];
      float b0=Ws[kk][cid], b1=Ws[kk][cid+32];
      acc[0][0]=fmaf(a4.x,b0,acc[0][0]); acc[0][1]=fmaf(a4.x,b1,acc[0][1]);
      acc[1][0]=fmaf(a4.y,b0,acc[1][0]); acc[1][1]=fmaf(a4.y,b1,acc[1][1]);
      acc[2][0]=fmaf(a4.z,b0,acc[2][0]); acc[2][1]=fmaf(a4.z,b1,acc[2][1]);
      acc[3][0]=fmaf(a4.w,b0,acc[3][0]); acc[3][1]=fmaf(a4.w,b1,acc[3][1]);
    }
    __syncthreads();
  }
  float bb0=bias[cb+cid], bb1=bias[cb+cid+32];
  #pragma unroll
  for (int r=0;r<4;++r){
    int row=s0+(rid<<2)+r;
    #pragma unroll
    for (int c=0;c<2;++c){
      int col=cb+cid+(c<<5);
      float v=acc[r][c]+(c?bb1:bb0);
      if (ACT==1) v=gelu_f(v);
      if (ACT==2) v=silu_f(v);
      if (RES) v+=res[(size_t)row*N+col];
      C[(size_t)row*N+col]=v;
    }
  }
}

// gated FFN elementwise
__global__ void __launch_bounds__(256) k_gate(const float* __restrict__ ff, float* __restrict__ gv){
  int idx=blockIdx.x*256+threadIdx.x;
  if (idx<S*2048){
    int s2=idx>>11, m=idx&2047;
    float g=ff[s2*4096+m], v=ff[s2*4096+2048+m];
    gv[idx]=silu_f(g)*v;
  }
}

extern "C" void kernel_launch(void* const* d_in, const int* in_sizes, int n_in,
                              void* d_out, int out_size, void* d_ws, size_t ws_size,
                              hipStream_t stream){
  const float* x   =(const float*)d_in[0];
  const float* pat =(const float*)d_in[1];
  const float* sw1 =(const float*)d_in[2];
  const float* sb1 =(const float*)d_in[3];
  const float* sw2 =(const float*)d_in[4];
  const float* sb2 =(const float*)d_in[5];
  const float* ww1 =(const float*)d_in[6];
  const float* wb1 =(const float*)d_in[7];
  const float* ww2 =(const float*)d_in[8];
  const float* wb2 =(const float*)d_in[9];
  const float* iw1 =(const float*)d_in[10];
  const float* ib1 =(const float*)d_in[11];
  const float* iw2 =(const float*)d_in[12];
  const float* ib2 =(const float*)d_in[13];
  const float* mw1 =(const float*)d_in[14];
  const float* mb1 =(const float*)d_in[15];
  const float* mw2 =(const float*)d_in[16];
  const float* mb2 =(const float*)d_in[17];
  const float* bank=(const float*)d_in[18];
  const float* upw =(const float*)d_in[19];
  const float* upb =(const float*)d_in[20];
  const float* dww =(const float*)d_in[21];
  const float* dwb =(const float*)d_in[22];
  const float* n1g =(const float*)d_in[23];
  const float* n1b =(const float*)d_in[24];
  const float* n2g =(const float*)d_in[25];
  const float* n2b =(const float*)d_in[26];
  float* out=(float*)d_out;

  float* w = (float*)d_ws;
  float* xn     = w;                 // 131072
  float* xr     = xn+131072;         // 131072
  float* meanxr = xr+131072;         // 512
  float* memmean= meanxr+512;        // 512
  float* pwb    = memmean+512;       // 4096
  float* inten  = pwb+4096;          // 256
  float* ctxsel = inten+256;         // 32
  float* ctxint = ctxsel+32;         // 64
  float* mempart= ctxint+64;         // 512
  float* co     = mempart+512;       // 131072
  float* h1     = co+131072;         // 131072
  float* co2    = h1+131072;         // 131072
  float* ff     = co2+131072;        // 1048576
  float* gv     = ff+1048576;        // 524288
  int*   kkp    = (int*)(gv+524288);          // 4
  unsigned* meta= (unsigned*)(kkp+4);         // 1024
  // zero-initialized region (single memset): ghist | goutr | gcount
  unsigned* ghist = (unsigned*)(meta+1024);   // 256*8192 = 2097152 u32
  float* goutr  = (float*)(ghist+2097152);    // 256*512  = 131072 f32
  unsigned* gcount=(unsigned*)(goutr+131072); // 256
  // stash (not zeroed)
  unsigned* gbits = gcount+256;               // 256*8192 u32
  float* gcon   = (float*)(gbits+2097152);    // 256*8192 f32
  unsigned short* grow = (unsigned short*)(gcon+2097152); // 256*8192 u16

  hipMemsetAsync(ghist, 0, (size_t)(2097152+131072+256)*4, stream);

  k_ln_rope<<<S,256,0,stream>>>(x,n1g,n1b,xn,xr);
  k_colmean<<<4,256,0,stream>>>(xr,bank,meanxr,memmean);
  k_head<<<1,256,0,stream>>>(meanxr,memmean,ww1,wb1,ww2,wb2,sw1,sb1,iw1,ib1,mw1,mb1,
                             ctxsel,ctxint,mempart,kkp);
  k_selint<<<S,256,0,stream>>>(xr,ctxsel,ctxint,sw1,sw2,sb2,iw1,iw2,ib2,pwb,inten);
  k_fhist<<<dim3(64,4),1024,0,stream>>>(pat,pwb,ghist);
  k_fth<<<S,256,0,stream>>>(ghist,kkp,(unsigned*)meta);
  k_fmv<<<dim3(64,4),1024,0,stream>>>(pat,pwb,xn,(unsigned*)meta,goutr,gbits,gcon,grow,gcount);
  k_fref<<<S,256,0,stream>>>(x,goutr,(unsigned*)meta,gcount,gbits,gcon,grow,inten,n2g,n2b,co);
  k_gemm2<2,0><<<dim3(8,8),256,0,stream>>>(co, mw1, mempart, nullptr, h1, 512, 512);
  k_gemm2<0,1><<<dim3(8,8),256,0,stream>>>(h1, mw2, mb2, co, co2, 512, 512);
  k_gemm2<0,0><<<dim3(64,8),256,0,stream>>>(co2, upw, upb, nullptr, ff, 512, 4096);
  k_gate<<<2048,256,0,stream>>>(ff,gv);
  k_gemm2<0,1><<<dim3(8,8),256,0,stream>>>(gv, dww, dwb, co2, out, 2048, 512);
}